// Round 1
// baseline (936.291 us; speedup 1.0000x reference)
//
#include <hip/hip_runtime.h>
#include <hip/hip_bf16.h>
#include <stdint.h>

#define L_SEQ 4096
#define H_DIM 768
#define N_HEADS 12
#define D_HEAD 64
#define N_CHUNK 32
#define CHUNK 128
#define FF_DIM 3072
#define OUT_DIM 384
#define BATCH 2
#define EPS_LN 1e-5f
#define M_ROWS (BATCH * L_SEQ)   /* 8192 */
#define QKV_LD (3 * H_DIM)       /* 2304 */

typedef unsigned short u16;
typedef __bf16 bx8 __attribute__((ext_vector_type(8)));
typedef float fx4 __attribute__((ext_vector_type(4)));
typedef u16 ux8 __attribute__((ext_vector_type(8)));

__device__ __forceinline__ u16 f2bf(float f) {
  union { float f; unsigned u; } x; x.f = f;
  unsigned r = x.u + 0x7fffu + ((x.u >> 16) & 1u);
  return (u16)(r >> 16);
}
__device__ __forceinline__ float bf2f(u16 v) {
  union { unsigned u; float f; } x; x.u = ((unsigned)v) << 16;
  return x.f;
}

__device__ __forceinline__ void gload16(const void* g, void* l) {
  __builtin_amdgcn_global_load_lds((const __attribute__((address_space(1))) void*)g,
                                   (__attribute__((address_space(3))) void*)l, 16, 0, 0);
}

// ---------------- GEMM: C(MxN) = A(MxK,bf16) @ Bt(NxK,bf16)^T + bias ----------------
// m97 structure: 128x128 tile, BK=32, 4 waves (2x2 of 64x64), global_load_lds w=16.
template<int OUT_BF16, int DO_GELU>
__global__ __launch_bounds__(256, 2)
void gemm_bf16_kernel(const u16* __restrict__ A, const u16* __restrict__ Bt,
                      const float* __restrict__ bias,
                      float* __restrict__ Cf, u16* __restrict__ Cb,
                      int N, int K)
{
  __shared__ __align__(16) u16 As[128 * 32];
  __shared__ __align__(16) u16 Bs[128 * 32];
  const int tid = threadIdx.x;
  const int lane = tid & 63, wave = tid >> 6;
  const int c16 = lane & 15, g = lane >> 4;
  const int nbn = N >> 7;
  int id = blockIdx.x;
  const int nwg = gridDim.x;
  id = (id & 7) * (nwg >> 3) + (id >> 3);   // XCD swizzle (all grids %8==0)
  const int bm = id / nbn, bn = id % nbn;
  const int wr = wave >> 1, wc = wave & 1;

  const u16* Ab = A + (size_t)(bm * 128) * K;
  const u16* Bb = Bt + (size_t)(bn * 128) * K;

  fx4 acc[4][4] = {};

  const int ch0 = wave * 64 + lane;
  const int ch1 = 256 + ch0;

  for (int k0 = 0; k0 < K; k0 += 32) {
    gload16(Ab + (size_t)(ch0 >> 2) * K + k0 + (ch0 & 3) * 8, &As[(size_t)(wave * 64) * 8]);
    gload16(Ab + (size_t)(ch1 >> 2) * K + k0 + (ch1 & 3) * 8, &As[(size_t)(256 + wave * 64) * 8]);
    gload16(Bb + (size_t)(ch0 >> 2) * K + k0 + (ch0 & 3) * 8, &Bs[(size_t)(wave * 64) * 8]);
    gload16(Bb + (size_t)(ch1 >> 2) * K + k0 + (ch1 & 3) * 8, &Bs[(size_t)(256 + wave * 64) * 8]);
    __syncthreads();
    bx8 af[4], bf[4];
    #pragma unroll
    for (int i = 0; i < 4; i++)
      af[i] = *(const bx8*)&As[(wr * 64 + i * 16 + c16) * 32 + g * 8];
    #pragma unroll
    for (int i = 0; i < 4; i++)
      bf[i] = *(const bx8*)&Bs[(wc * 64 + i * 16 + c16) * 32 + g * 8];
    #pragma unroll
    for (int mi = 0; mi < 4; mi++)
      #pragma unroll
      for (int ni = 0; ni < 4; ni++)
        acc[mi][ni] = __builtin_amdgcn_mfma_f32_16x16x32_bf16(af[mi], bf[ni], acc[mi][ni], 0, 0, 0);
    __syncthreads();
  }

  const int row0 = bm * 128 + wr * 64 + g * 4;
  const int col0 = bn * 128 + wc * 64 + c16;
  #pragma unroll
  for (int ni = 0; ni < 4; ni++) {
    const int col = col0 + ni * 16;
    const float bb = bias[col];
    #pragma unroll
    for (int mi = 0; mi < 4; mi++) {
      #pragma unroll
      for (int r = 0; r < 4; r++) {
        float y = acc[mi][ni][r] + bb;
        if (DO_GELU) {
          const float t = y;
          y = 0.5f * t * (1.0f + tanhf(0.7978845608f * (t + 0.044715f * t * t * t)));
        }
        const size_t idx = (size_t)(row0 + mi * 16 + r) * N + col;
        if (OUT_BF16) Cb[idx] = f2bf(y);
        else Cf[idx] = y;
      }
    }
  }
}

// ---------------- Local (windowed) attention ----------------
// block = (b, h, chunk). 8 waves x 16 query rows. 416 ext keys:
//   0..383 local window [(n-1)*C, (n+2)*C), 384 = global k0, 385..415 pad.
#define V_STR 424

__global__ __launch_bounds__(512, 2)
void attn_local_kernel(const u16* __restrict__ qkv, const int* __restrict__ amask,
                       u16* __restrict__ attnout)
{
  __shared__ __align__(16) u16 Vlds[64 * V_STR];        // V^T: [d][key]
  __shared__ __align__(16) u16 Plds[8 * 16 * V_STR];    // per-wave P: [q][key]

  const int tid = threadIdx.x;
  const int lane = tid & 63, w = tid >> 6;
  const int c16 = lane & 15, g = lane >> 4;

  const int bh = blockIdx.x >> 5;
  const int n = blockIdx.x & 31;
  const int b = bh / N_HEADS, h = bh % N_HEADS;

  const u16* qkvb = qkv + (size_t)b * L_SEQ * QKV_LD + h * D_HEAD;
  const int chunk_lo = n * CHUNK - CHUNK;

  // stage V^T (+ v0 at col 384, zeros at 385..415)
  for (int idx = tid; idx < 416 * 8; idx += 512) {
    const int j = idx >> 3, d8 = (idx & 7) * 8;
    if (j >= 385) {
      #pragma unroll
      for (int i = 0; i < 8; i++) Vlds[(d8 + i) * V_STR + j] = 0;
    } else {
      int pos = (j == 384) ? 0 : chunk_lo + j;
      if (pos < 0 || pos >= L_SEQ) pos = 0;   // masked later -> P=0
      ux8 vv = *(const ux8*)(qkvb + (size_t)pos * QKV_LD + 2 * H_DIM + d8);
      #pragma unroll
      for (int i = 0; i < 8; i++) Vlds[(d8 + i) * V_STR + j] = vv[i];
    }
  }

  // Q fragments (A-layout: row=lane&15, k=d=(lane>>4)*8+i)
  const int qrow = n * CHUNK + w * 16 + c16;
  const u16* qp = qkvb + (size_t)qrow * QKV_LD + g * 8;
  const bx8 aq0 = *(const bx8*)qp;
  const bx8 aq1 = *(const bx8*)(qp + 32);

  // per-lane key-column validity for its 24 local fragments
  unsigned kvm = 0;
  #pragma unroll
  for (int kf = 0; kf < 24; kf++) {
    const int pos = chunk_lo + kf * 16 + c16;
    bool ok = (pos >= 1) && (pos < L_SEQ);
    if (ok) ok = (amask[b * L_SEQ + pos] > 0);
    kvm |= ((unsigned)ok) << kf;
  }

  // QK^T: B fragments straight from global (col=lane&15 -> key row, k=d)
  fx4 s[26];
  #pragma unroll
  for (int kf = 0; kf < 25; kf++) {
    int pos = (kf == 24) ? 0 : chunk_lo + kf * 16 + c16;
    if (pos < 0 || pos >= L_SEQ) pos = 0;
    const u16* kp = qkvb + (size_t)pos * QKV_LD + H_DIM + g * 8;
    const bx8 b0 = *(const bx8*)kp;
    const bx8 b1 = *(const bx8*)(kp + 32);
    fx4 a = {};
    a = __builtin_amdgcn_mfma_f32_16x16x32_bf16(aq0, b0, a, 0, 0, 0);
    a = __builtin_amdgcn_mfma_f32_16x16x32_bf16(aq1, b1, a, 0, 0, 0);
    s[kf] = a;
  }

  // mask + row softmax (row r of lane-group g = query c = w*16+g*4+r)
  const int cq = w * 16 + g * 4;
  float mx[4], sm[4];
  #pragma unroll
  for (int r = 0; r < 4; r++) mx[r] = -3.0e38f;
  #pragma unroll
  for (int kf = 0; kf < 25; kf++) {
    const int j = kf * 16 + c16;
    const bool kv = (kf < 24) ? (((kvm >> kf) & 1u) != 0) : (c16 == 0);
    #pragma unroll
    for (int r = 0; r < 4; r++) {
      const int c = cq + r;
      const bool keep = kv && (kf == 24 || (j >= c && j <= c + 256));
      const float val = keep ? s[kf][r] * 0.125f : -1.0e9f;
      s[kf][r] = val;
      mx[r] = fmaxf(mx[r], val);
    }
  }
  #pragma unroll
  for (int r = 0; r < 4; r++) {
    float m = mx[r];
    m = fmaxf(m, __shfl_xor(m, 1));
    m = fmaxf(m, __shfl_xor(m, 2));
    m = fmaxf(m, __shfl_xor(m, 4));
    m = fmaxf(m, __shfl_xor(m, 8));
    mx[r] = m;
    sm[r] = 0.f;
  }
  #pragma unroll
  for (int kf = 0; kf < 25; kf++)
    #pragma unroll
    for (int r = 0; r < 4; r++) {
      const float p = __expf(s[kf][r] - mx[r]);
      s[kf][r] = p;
      sm[r] += p;
    }
  float rinv[4];
  #pragma unroll
  for (int r = 0; r < 4; r++) {
    float t = sm[r];
    t += __shfl_xor(t, 1);
    t += __shfl_xor(t, 2);
    t += __shfl_xor(t, 4);
    t += __shfl_xor(t, 8);
    rinv[r] = 1.0f / t;
  }
  s[25] = (fx4){0.f, 0.f, 0.f, 0.f};

  // P -> LDS (unnormalized, bf16), C-layout scatter
  u16* pb = Plds + (size_t)w * 16 * V_STR;
  #pragma unroll
  for (int kf = 0; kf < 26; kf++) {
    const int j = kf * 16 + c16;
    #pragma unroll
    for (int r = 0; r < 4; r++)
      pb[(g * 4 + r) * V_STR + j] = f2bf(s[kf][r]);
  }
  __syncthreads();

  // PV: A = P (row=query), B = V^T rows
  fx4 o[4] = {};
  const u16* pr = Plds + (size_t)(w * 16 + c16) * V_STR + g * 8;
  #pragma unroll
  for (int kt = 0; kt < 13; kt++) {
    const bx8 pa = *(const bx8*)(pr + kt * 32);
    #pragma unroll
    for (int df = 0; df < 4; df++) {
      const bx8 vvf = *(const bx8*)&Vlds[(df * 16 + c16) * V_STR + kt * 32 + g * 8];
      o[df] = __builtin_amdgcn_mfma_f32_16x16x32_bf16(pa, vvf, o[df], 0, 0, 0);
    }
  }

  // write out in (B, L, NH*DH) layout
  u16* ob = attnout + (size_t)b * L_SEQ * H_DIM + h * D_HEAD;
  const int posq = n * CHUNK + w * 16 + g * 4;
  #pragma unroll
  for (int df = 0; df < 4; df++)
    #pragma unroll
    for (int r = 0; r < 4; r++)
      ob[(size_t)(posq + r) * H_DIM + df * 16 + c16] = f2bf(o[df][r] * rinv[r]);
}

// ---------------- Global row (query position 0): full attention over L ----------------
__global__ __launch_bounds__(256)
void attn_global_row_kernel(const u16* __restrict__ qkv, const int* __restrict__ amask,
                            u16* __restrict__ attnout)
{
  __shared__ float ps[L_SEQ];
  __shared__ float qs[D_HEAD];
  __shared__ float oacc[4][D_HEAD];
  __shared__ float red[8];

  const int tid = threadIdx.x;
  const int b = blockIdx.x / N_HEADS, h = blockIdx.x % N_HEADS;
  const u16* base = qkv + (size_t)b * L_SEQ * QKV_LD + h * D_HEAD;

  if (tid < D_HEAD) qs[tid] = bf2f(base[tid]);
  __syncthreads();

  float lmax = -3.0e38f;
  for (int l = tid; l < L_SEQ; l += 256) {
    const ux8* kp = (const ux8*)(base + (size_t)l * QKV_LD + H_DIM);
    float dot = 0.f;
    #pragma unroll
    for (int i = 0; i < 8; i++) {
      const ux8 kv = kp[i];
      #pragma unroll
      for (int jj = 0; jj < 8; jj++) dot += qs[i * 8 + jj] * bf2f(kv[jj]);
    }
    float sv = dot * 0.125f;
    if (amask[b * L_SEQ + l] == 0) sv = -1.0e9f;
    ps[l] = sv;
    lmax = fmaxf(lmax, sv);
  }
  #pragma unroll
  for (int off = 32; off > 0; off >>= 1) lmax = fmaxf(lmax, __shfl_xor(lmax, off));
  if ((tid & 63) == 0) red[tid >> 6] = lmax;
  __syncthreads();
  const float M = fmaxf(fmaxf(red[0], red[1]), fmaxf(red[2], red[3]));
  float lsum = 0.f;
  for (int l = tid; l < L_SEQ; l += 256) {
    const float e = __expf(ps[l] - M);
    ps[l] = e;
    lsum += e;
  }
  #pragma unroll
  for (int off = 32; off > 0; off >>= 1) lsum += __shfl_xor(lsum, off);
  if ((tid & 63) == 0) red[4 + (tid >> 6)] = lsum;
  __syncthreads();
  const float S = red[4] + red[5] + red[6] + red[7];

  const int d = tid & 63, seg = tid >> 6;
  float acc = 0.f;
  const u16* vb = base + 2 * H_DIM + d;
  for (int l = seg * 1024; l < seg * 1024 + 1024; l++)
    acc += ps[l] * bf2f(vb[(size_t)l * QKV_LD]);
  oacc[seg][d] = acc;
  __syncthreads();
  if (tid < D_HEAD) {
    const float y = (oacc[0][tid] + oacc[1][tid] + oacc[2][tid] + oacc[3][tid]) / S;
    attnout[(size_t)b * L_SEQ * H_DIM + h * D_HEAD + tid] = f2bf(y);
  }
}

// ---------------- LayerNorm kernels ----------------
__device__ __forceinline__ void block_stats(float sum, float sq, float* red,
                                            float& mean, float& rstd)
{
  const int lane = threadIdx.x & 63, wv = threadIdx.x >> 6;
  #pragma unroll
  for (int off = 32; off > 0; off >>= 1) {
    sum += __shfl_xor(sum, off);
    sq  += __shfl_xor(sq, off);
  }
  if (lane == 0) { red[wv] = sum; red[4 + wv] = sq; }
  __syncthreads();
  sum = red[0] + red[1] + red[2] + red[3];
  sq  = red[4] + red[5] + red[6] + red[7];
  mean = sum * (1.0f / H_DIM);
  const float var = sq * (1.0f / H_DIM) - mean * mean;
  rstd = rsqrtf(var + EPS_LN);
}

__global__ __launch_bounds__(256)
void embed_ln_kernel(const int* __restrict__ ids, const float* __restrict__ wemb,
                     const float* __restrict__ pemb, const float* __restrict__ gam,
                     const float* __restrict__ bet, float* __restrict__ xf,
                     u16* __restrict__ xb)
{
  __shared__ float red[8];
  const int row = blockIdx.x, tid = threadIdx.x;
  const int l = row & (L_SEQ - 1);
  const int id = ids[row];
  float v[3]; float sum = 0.f, sq = 0.f;
  #pragma unroll
  for (int i = 0; i < 3; i++) {
    const int c = tid + i * 256;
    const float t = wemb[(size_t)id * H_DIM + c] + pemb[(size_t)l * H_DIM + c];
    v[i] = t; sum += t; sq += t * t;
  }
  float mean, rstd;
  block_stats(sum, sq, red, mean, rstd);
  #pragma unroll
  for (int i = 0; i < 3; i++) {
    const int c = tid + i * 256;
    const float y = (v[i] - mean) * rstd * gam[c] + bet[c];
    xf[(size_t)row * H_DIM + c] = y;
    xb[(size_t)row * H_DIM + c] = f2bf(y);
  }
}

__global__ __launch_bounds__(256)
void add_ln_kernel(float* xio, const float* __restrict__ yin,
                   const float* __restrict__ gam, const float* __restrict__ bet,
                   u16* __restrict__ xb)
{
  __shared__ float red[8];
  const int row = blockIdx.x, tid = threadIdx.x;
  float v[3]; float sum = 0.f, sq = 0.f;
  #pragma unroll
  for (int i = 0; i < 3; i++) {
    const int c = tid + i * 256;
    const float t = xio[(size_t)row * H_DIM + c] + yin[(size_t)row * H_DIM + c];
    v[i] = t; sum += t; sq += t * t;
  }
  float mean, rstd;
  block_stats(sum, sq, red, mean, rstd);
  #pragma unroll
  for (int i = 0; i < 3; i++) {
    const int c = tid + i * 256;
    const float y = (v[i] - mean) * rstd * gam[c] + bet[c];
    xio[(size_t)row * H_DIM + c] = y;
    xb[(size_t)row * H_DIM + c] = f2bf(y);
  }
}

// ---------------- weight transpose fp32 -> bf16 (Wt[n][k] = W[k][n]) ----------------
__global__ __launch_bounds__(256)
void transpose_w_kernel(const float* __restrict__ W, u16* __restrict__ Wt, int K, int N)
{
  __shared__ float tile[32][33];
  const int k0 = blockIdx.x * 32, n0 = blockIdx.y * 32;
  const int tx = threadIdx.x & 31, ty = threadIdx.x >> 5;
  #pragma unroll
  for (int i = 0; i < 32; i += 8)
    tile[ty + i][tx] = W[(size_t)(k0 + ty + i) * N + n0 + tx];
  __syncthreads();
  #pragma unroll
  for (int i = 0; i < 32; i += 8)
    Wt[(size_t)(n0 + ty + i) * K + k0 + tx] = f2bf(tile[tx][ty + i]);
}

__global__ void concat3_kernel(const float* __restrict__ a, const float* __restrict__ b,
                               const float* __restrict__ c, float* __restrict__ out)
{
  const int i = blockIdx.x * 256 + threadIdx.x;
  if (i < H_DIM) out[i] = a[i];
  else if (i < 2 * H_DIM) out[i] = b[i - H_DIM];
  else if (i < 3 * H_DIM) out[i] = c[i - 2 * H_DIM];
}

__global__ void cls_copy_kernel(const float* __restrict__ vdn, float* __restrict__ cls)
{
  const int i = blockIdx.x * 256 + threadIdx.x;
  if (i < BATCH * OUT_DIM)
    cls[i] = vdn[(size_t)(i / OUT_DIM) * L_SEQ * OUT_DIM + (i % OUT_DIM)];
}

// ---------------- host ----------------
extern "C" void kernel_launch(void* const* d_in, const int* in_sizes, int n_in,
                              void* d_out, int out_size, void* d_ws, size_t ws_size,
                              hipStream_t stream)
{
  (void)in_sizes; (void)n_in; (void)out_size; (void)ws_size;
  const int*   ids   = (const int*)d_in[0];
  const int*   amask = (const int*)d_in[1];
  const float* wemb  = (const float*)d_in[2];
  const float* pemb  = (const float*)d_in[3];
  const float* elns  = (const float*)d_in[4];
  const float* elnb  = (const float*)d_in[5];
  const float* Wq    = (const float*)d_in[6];
  const float* bq    = (const float*)d_in[7];
  const float* Wk    = (const float*)d_in[8];
  const float* bk    = (const float*)d_in[9];
  const float* Wv    = (const float*)d_in[10];
  const float* bv    = (const float*)d_in[11];
  const float* Wo    = (const float*)d_in[12];
  const float* bo    = (const float*)d_in[13];
  const float* ln1s  = (const float*)d_in[14];
  const float* ln1b  = (const float*)d_in[15];
  const float* W1    = (const float*)d_in[16];
  const float* b1    = (const float*)d_in[17];
  const float* W2    = (const float*)d_in[18];
  const float* b2    = (const float*)d_in[19];
  const float* ln2s  = (const float*)d_in[20];
  const float* ln2b  = (const float*)d_in[21];
  const float* Wfc   = (const float*)d_in[22];
  const float* bfc   = (const float*)d_in[23];

  char* ws = (char*)d_ws;
  size_t off = 0;
  auto alloc = [&](size_t bytes) -> void* {
    void* p = ws + off;
    off += (bytes + 255) & ~(size_t)255;
    return p;
  };
  float* xf   = (float*)alloc((size_t)M_ROWS * H_DIM * 4);
  float* proj = (float*)alloc((size_t)M_ROWS * H_DIM * 4);
  u16* xb     = (u16*)alloc((size_t)M_ROWS * H_DIM * 2);
  u16* big    = (u16*)alloc((size_t)M_ROWS * FF_DIM * 2);  // qkv(2304) / ff1(3072) time-share
  u16* attno  = (u16*)alloc((size_t)M_ROWS * H_DIM * 2);
  u16* wqkvT  = (u16*)alloc((size_t)QKV_LD * H_DIM * 2);
  u16* woT    = (u16*)alloc((size_t)H_DIM * H_DIM * 2);
  u16* w1T    = (u16*)alloc((size_t)FF_DIM * H_DIM * 2);
  u16* w2T    = (u16*)alloc((size_t)H_DIM * FF_DIM * 2);
  u16* wfcT   = (u16*)alloc((size_t)OUT_DIM * H_DIM * 2);
  float* bqkv = (float*)alloc(QKV_LD * 4);

  u16* qkvb = big;
  u16* ff1  = big;

  embed_ln_kernel<<<M_ROWS, 256, 0, stream>>>(ids, wemb, pemb, elns, elnb, xf, xb);

  for (int l = 0; l < 2; l++) {
    const size_t wof = (size_t)l * H_DIM * H_DIM;
    transpose_w_kernel<<<dim3(24, 24), 256, 0, stream>>>(Wq + wof, wqkvT, H_DIM, H_DIM);
    transpose_w_kernel<<<dim3(24, 24), 256, 0, stream>>>(Wk + wof, wqkvT + (size_t)H_DIM * H_DIM, H_DIM, H_DIM);
    transpose_w_kernel<<<dim3(24, 24), 256, 0, stream>>>(Wv + wof, wqkvT + (size_t)2 * H_DIM * H_DIM, H_DIM, H_DIM);
    transpose_w_kernel<<<dim3(24, 24), 256, 0, stream>>>(Wo + wof, woT, H_DIM, H_DIM);
    transpose_w_kernel<<<dim3(24, 96), 256, 0, stream>>>(W1 + (size_t)l * H_DIM * FF_DIM, w1T, H_DIM, FF_DIM);
    transpose_w_kernel<<<dim3(96, 24), 256, 0, stream>>>(W2 + (size_t)l * FF_DIM * H_DIM, w2T, FF_DIM, H_DIM);
    concat3_kernel<<<9, 256, 0, stream>>>(bq + l * H_DIM, bk + l * H_DIM, bv + l * H_DIM, bqkv);

    gemm_bf16_kernel<1, 0><<<(M_ROWS / 128) * (QKV_LD / 128), 256, 0, stream>>>(
        xb, wqkvT, bqkv, nullptr, qkvb, QKV_LD, H_DIM);
    attn_local_kernel<<<BATCH * N_HEADS * N_CHUNK, 512, 0, stream>>>(qkvb, amask, attno);
    attn_global_row_kernel<<<BATCH * N_HEADS, 256, 0, stream>>>(qkvb, amask, attno);
    gemm_bf16_kernel<0, 0><<<(M_ROWS / 128) * (H_DIM / 128), 256, 0, stream>>>(
        attno, woT, bo + l * H_DIM, proj, nullptr, H_DIM, H_DIM);
    add_ln_kernel<<<M_ROWS, 256, 0, stream>>>(xf, proj, ln1s + l * H_DIM, ln1b + l * H_DIM, xb);
    gemm_bf16_kernel<1, 1><<<(M_ROWS / 128) * (FF_DIM / 128), 256, 0, stream>>>(
        xb, w1T, b1 + l * FF_DIM, nullptr, ff1, FF_DIM, H_DIM);
    gemm_bf16_kernel<0, 0><<<(M_ROWS / 128) * (H_DIM / 128), 256, 0, stream>>>(
        ff1, w2T, b2 + l * H_DIM, proj, nullptr, H_DIM, FF_DIM);
    add_ln_kernel<<<M_ROWS, 256, 0, stream>>>(xf, proj, ln2s + l * H_DIM, ln2b + l * H_DIM, xb);
  }

  transpose_w_kernel<<<dim3(24, 12), 256, 0, stream>>>(Wfc, wfcT, H_DIM, OUT_DIM);
  float* vdn = (float*)d_out;
  gemm_bf16_kernel<0, 0><<<(M_ROWS / 128) * (OUT_DIM / 128), 256, 0, stream>>>(
      xb, wfcT, bfc, vdn, nullptr, OUT_DIM, H_DIM);
  cls_copy_kernel<<<3, 256, 0, stream>>>(vdn, vdn + (size_t)BATCH * L_SEQ * OUT_DIM);
}

// Round 2
// 730.429 us; speedup vs baseline: 1.2818x; 1.2818x over previous
//
#include <hip/hip_runtime.h>
#include <hip/hip_bf16.h>
#include <stdint.h>

#define L_SEQ 4096
#define H_DIM 768
#define N_HEADS 12
#define D_HEAD 64
#define N_CHUNK 32
#define CHUNK 128
#define FF_DIM 3072
#define OUT_DIM 384
#define BATCH 2
#define EPS_LN 1e-5f
#define M_ROWS (BATCH * L_SEQ)   /* 8192 */
#define QKV_LD (3 * H_DIM)       /* 2304 */
#define NSEG 16                   /* global-row segments: 4096/256 */

typedef unsigned short u16;
typedef __bf16 bx8 __attribute__((ext_vector_type(8)));
typedef float fx4 __attribute__((ext_vector_type(4)));
typedef u16 ux8 __attribute__((ext_vector_type(8)));

__device__ __forceinline__ u16 f2bf(float f) {
  union { float f; unsigned u; } x; x.f = f;
  unsigned r = x.u + 0x7fffu + ((x.u >> 16) & 1u);
  return (u16)(r >> 16);
}
__device__ __forceinline__ float bf2f(u16 v) {
  union { unsigned u; float f; } x; x.u = ((unsigned)v) << 16;
  return x.f;
}

__device__ __forceinline__ void gload16(const void* g, void* l) {
  __builtin_amdgcn_global_load_lds((const __attribute__((address_space(1))) void*)g,
                                   (__attribute__((address_space(3))) void*)l, 16, 0, 0);
}

// ---------------- GEMM: C(MxN) = A(MxK,bf16) @ Bt(NxK,bf16)^T + bias ----------------
// m97 structure: 128x128 tile, BK=32, 4 waves (2x2 of 64x64), global_load_lds w=16.
template<int OUT_BF16, int DO_GELU>
__global__ __launch_bounds__(256, 2)
void gemm_bf16_kernel(const u16* __restrict__ A, const u16* __restrict__ Bt,
                      const float* __restrict__ bias,
                      float* __restrict__ Cf, u16* __restrict__ Cb,
                      int N, int K)
{
  __shared__ __align__(16) u16 As[128 * 32];
  __shared__ __align__(16) u16 Bs[128 * 32];
  const int tid = threadIdx.x;
  const int lane = tid & 63, wave = tid >> 6;
  const int c16 = lane & 15, g = lane >> 4;
  const int nbn = N >> 7;
  int id = blockIdx.x;
  const int nwg = gridDim.x;
  id = (id & 7) * (nwg >> 3) + (id >> 3);   // XCD swizzle (all grids %8==0)
  const int bm = id / nbn, bn = id % nbn;
  const int wr = wave >> 1, wc = wave & 1;

  const u16* Ab = A + (size_t)(bm * 128) * K;
  const u16* Bb = Bt + (size_t)(bn * 128) * K;

  fx4 acc[4][4] = {};

  const int ch0 = wave * 64 + lane;
  const int ch1 = 256 + ch0;

  for (int k0 = 0; k0 < K; k0 += 32) {
    gload16(Ab + (size_t)(ch0 >> 2) * K + k0 + (ch0 & 3) * 8, &As[(size_t)(wave * 64) * 8]);
    gload16(Ab + (size_t)(ch1 >> 2) * K + k0 + (ch1 & 3) * 8, &As[(size_t)(256 + wave * 64) * 8]);
    gload16(Bb + (size_t)(ch0 >> 2) * K + k0 + (ch0 & 3) * 8, &Bs[(size_t)(wave * 64) * 8]);
    gload16(Bb + (size_t)(ch1 >> 2) * K + k0 + (ch1 & 3) * 8, &Bs[(size_t)(256 + wave * 64) * 8]);
    __syncthreads();
    bx8 af[4], bf[4];
    #pragma unroll
    for (int i = 0; i < 4; i++)
      af[i] = *(const bx8*)&As[(wr * 64 + i * 16 + c16) * 32 + g * 8];
    #pragma unroll
    for (int i = 0; i < 4; i++)
      bf[i] = *(const bx8*)&Bs[(wc * 64 + i * 16 + c16) * 32 + g * 8];
    #pragma unroll
    for (int mi = 0; mi < 4; mi++)
      #pragma unroll
      for (int ni = 0; ni < 4; ni++)
        acc[mi][ni] = __builtin_amdgcn_mfma_f32_16x16x32_bf16(af[mi], bf[ni], acc[mi][ni], 0, 0, 0);
    __syncthreads();
  }

  const int row0 = bm * 128 + wr * 64 + g * 4;
  const int col0 = bn * 128 + wc * 64 + c16;
  #pragma unroll
  for (int ni = 0; ni < 4; ni++) {
    const int col = col0 + ni * 16;
    const float bb = bias[col];
    #pragma unroll
    for (int mi = 0; mi < 4; mi++) {
      #pragma unroll
      for (int r = 0; r < 4; r++) {
        float y = acc[mi][ni][r] + bb;
        if (DO_GELU) {
          const float t = y;
          y = 0.5f * t * (1.0f + tanhf(0.7978845608f * (t + 0.044715f * t * t * t)));
        }
        const size_t idx = (size_t)(row0 + mi * 16 + r) * N + col;
        if (OUT_BF16) Cb[idx] = f2bf(y);
        else Cf[idx] = y;
      }
    }
  }
}

// ---------------- Local (windowed) attention ----------------
// block = (b, h, chunk). 8 waves x 16 query rows. 416 ext keys:
//   0..383 local window [(n-1)*C, (n+2)*C), 384 = global k0, 385..415 pad.
#define V_STR 424

__global__ __launch_bounds__(512, 2)
void attn_local_kernel(const u16* __restrict__ qkv, const int* __restrict__ amask,
                       u16* __restrict__ attnout)
{
  __shared__ __align__(16) u16 Vlds[64 * V_STR];        // V^T: [d][key]
  __shared__ __align__(16) u16 Plds[8 * 16 * V_STR];    // per-wave P: [q][key]

  const int tid = threadIdx.x;
  const int lane = tid & 63, w = tid >> 6;
  const int c16 = lane & 15, g = lane >> 4;

  const int bh = blockIdx.x >> 5;
  const int n = blockIdx.x & 31;
  const int b = bh / N_HEADS, h = bh % N_HEADS;

  const u16* qkvb = qkv + (size_t)b * L_SEQ * QKV_LD + h * D_HEAD;
  const int chunk_lo = n * CHUNK - CHUNK;

  // stage V^T (+ v0 at col 384, zeros at 385..415)
  for (int idx = tid; idx < 416 * 8; idx += 512) {
    const int j = idx >> 3, d8 = (idx & 7) * 8;
    if (j >= 385) {
      #pragma unroll
      for (int i = 0; i < 8; i++) Vlds[(d8 + i) * V_STR + j] = 0;
    } else {
      int pos = (j == 384) ? 0 : chunk_lo + j;
      if (pos < 0 || pos >= L_SEQ) pos = 0;   // masked later -> P=0
      ux8 vv = *(const ux8*)(qkvb + (size_t)pos * QKV_LD + 2 * H_DIM + d8);
      #pragma unroll
      for (int i = 0; i < 8; i++) Vlds[(d8 + i) * V_STR + j] = vv[i];
    }
  }

  // Q fragments (A-layout: row=lane&15, k=d=(lane>>4)*8+i)
  const int qrow = n * CHUNK + w * 16 + c16;
  const u16* qp = qkvb + (size_t)qrow * QKV_LD + g * 8;
  const bx8 aq0 = *(const bx8*)qp;
  const bx8 aq1 = *(const bx8*)(qp + 32);

  // per-lane key-column validity for its 24 local fragments
  unsigned kvm = 0;
  #pragma unroll
  for (int kf = 0; kf < 24; kf++) {
    const int pos = chunk_lo + kf * 16 + c16;
    bool ok = (pos >= 1) && (pos < L_SEQ);
    if (ok) ok = (amask[b * L_SEQ + pos] > 0);
    kvm |= ((unsigned)ok) << kf;
  }

  // QK^T: B fragments straight from global (col=lane&15 -> key row, k=d)
  fx4 s[26];
  #pragma unroll
  for (int kf = 0; kf < 25; kf++) {
    int pos = (kf == 24) ? 0 : chunk_lo + kf * 16 + c16;
    if (pos < 0 || pos >= L_SEQ) pos = 0;
    const u16* kp = qkvb + (size_t)pos * QKV_LD + H_DIM + g * 8;
    const bx8 b0 = *(const bx8*)kp;
    const bx8 b1 = *(const bx8*)(kp + 32);
    fx4 a = {};
    a = __builtin_amdgcn_mfma_f32_16x16x32_bf16(aq0, b0, a, 0, 0, 0);
    a = __builtin_amdgcn_mfma_f32_16x16x32_bf16(aq1, b1, a, 0, 0, 0);
    s[kf] = a;
  }

  // mask + row softmax (row r of lane-group g = query c = w*16+g*4+r)
  const int cq = w * 16 + g * 4;
  float mx[4], sm[4];
  #pragma unroll
  for (int r = 0; r < 4; r++) mx[r] = -3.0e38f;
  #pragma unroll
  for (int kf = 0; kf < 25; kf++) {
    const int j = kf * 16 + c16;
    const bool kv = (kf < 24) ? (((kvm >> kf) & 1u) != 0) : (c16 == 0);
    #pragma unroll
    for (int r = 0; r < 4; r++) {
      const int c = cq + r;
      const bool keep = kv && (kf == 24 || (j >= c && j <= c + 256));
      const float val = keep ? s[kf][r] * 0.125f : -1.0e9f;
      s[kf][r] = val;
      mx[r] = fmaxf(mx[r], val);
    }
  }
  #pragma unroll
  for (int r = 0; r < 4; r++) {
    float m = mx[r];
    m = fmaxf(m, __shfl_xor(m, 1));
    m = fmaxf(m, __shfl_xor(m, 2));
    m = fmaxf(m, __shfl_xor(m, 4));
    m = fmaxf(m, __shfl_xor(m, 8));
    mx[r] = m;
    sm[r] = 0.f;
  }
  #pragma unroll
  for (int kf = 0; kf < 25; kf++)
    #pragma unroll
    for (int r = 0; r < 4; r++) {
      const float p = __expf(s[kf][r] - mx[r]);
      s[kf][r] = p;
      sm[r] += p;
    }
  float rinv[4];
  #pragma unroll
  for (int r = 0; r < 4; r++) {
    float t = sm[r];
    t += __shfl_xor(t, 1);
    t += __shfl_xor(t, 2);
    t += __shfl_xor(t, 4);
    t += __shfl_xor(t, 8);
    rinv[r] = 1.0f / t;
  }
  s[25] = (fx4){0.f, 0.f, 0.f, 0.f};

  // P -> LDS (unnormalized, bf16), C-layout scatter
  u16* pb = Plds + (size_t)w * 16 * V_STR;
  #pragma unroll
  for (int kf = 0; kf < 26; kf++) {
    const int j = kf * 16 + c16;
    #pragma unroll
    for (int r = 0; r < 4; r++)
      pb[(g * 4 + r) * V_STR + j] = f2bf(s[kf][r]);
  }
  __syncthreads();

  // PV: A = P (row=query), B = V^T rows
  fx4 o[4] = {};
  const u16* pr = Plds + (size_t)(w * 16 + c16) * V_STR + g * 8;
  #pragma unroll
  for (int kt = 0; kt < 13; kt++) {
    const bx8 pa = *(const bx8*)(pr + kt * 32);
    #pragma unroll
    for (int df = 0; df < 4; df++) {
      const bx8 vvf = *(const bx8*)&Vlds[(df * 16 + c16) * V_STR + kt * 32 + g * 8];
      o[df] = __builtin_amdgcn_mfma_f32_16x16x32_bf16(pa, vvf, o[df], 0, 0, 0);
    }
  }

  // write out in (B, L, NH*DH) layout
  u16* ob = attnout + (size_t)b * L_SEQ * H_DIM + h * D_HEAD;
  const int posq = n * CHUNK + w * 16 + g * 4;
  #pragma unroll
  for (int df = 0; df < 4; df++)
    #pragma unroll
    for (int r = 0; r < 4; r++)
      ob[(size_t)(posq + r) * H_DIM + df * 16 + c16] = f2bf(o[df][r] * rinv[r]);
}

// ---------------- Global row (query position 0): full attention over L ----------------
// Split across L into NSEG segments x 24 (b,h) for parallelism (was 24 blocks,
// 1% occupancy, 120 us/dispatch). Deterministic fixed-order reductions.

// Pass 1: scores s0[l] = q0 . k_l * scale (masked), per-segment max.
__global__ __launch_bounds__(256)
void attn_g_score(const u16* __restrict__ qkv, const int* __restrict__ amask,
                  float* __restrict__ sbuf, float* __restrict__ pmax)
{
  __shared__ float qs[D_HEAD];
  __shared__ float red[4];
  const int seg = blockIdx.x, bh = blockIdx.y;
  const int b = bh / N_HEADS, h = bh % N_HEADS;
  const u16* base = qkv + (size_t)b * L_SEQ * QKV_LD + h * D_HEAD;
  const int tid = threadIdx.x;

  if (tid < D_HEAD) qs[tid] = bf2f(base[tid]);
  __syncthreads();

  const int l = seg * 256 + tid;
  const ux8* kp = (const ux8*)(base + (size_t)l * QKV_LD + H_DIM);
  float dot = 0.f;
  #pragma unroll
  for (int i = 0; i < 8; i++) {
    const ux8 kv = kp[i];
    #pragma unroll
    for (int j = 0; j < 8; j++) dot += qs[i * 8 + j] * bf2f(kv[j]);
  }
  float sv = dot * 0.125f;
  if (amask[b * L_SEQ + l] == 0) sv = -1.0e9f;
  sbuf[(size_t)bh * L_SEQ + l] = sv;

  float m = sv;
  #pragma unroll
  for (int off = 32; off > 0; off >>= 1) m = fmaxf(m, __shfl_xor(m, off));
  if ((tid & 63) == 0) red[tid >> 6] = m;
  __syncthreads();
  if (tid == 0)
    pmax[bh * NSEG + seg] = fmaxf(fmaxf(red[0], red[1]), fmaxf(red[2], red[3]));
}

// Pass 2: e = exp(s - M); per-segment expsum + partial o (4 lane-groups x 64 d).
__global__ __launch_bounds__(256)
void attn_g_pv(const u16* __restrict__ qkv, const float* __restrict__ sbuf,
               const float* __restrict__ pmax, float* __restrict__ psum,
               float* __restrict__ po)
{
  __shared__ float es[256];
  __shared__ float red[4];
  const int seg = blockIdx.x, bh = blockIdx.y;
  const int b = bh / N_HEADS, h = bh % N_HEADS;
  const int tid = threadIdx.x;

  float M = -3.0e38f;
  #pragma unroll
  for (int i = 0; i < NSEG; i++) M = fmaxf(M, pmax[bh * NSEG + i]);

  const int l = seg * 256 + tid;
  const float e = __expf(sbuf[(size_t)bh * L_SEQ + l] - M);
  es[tid] = e;

  float t = e;
  #pragma unroll
  for (int off = 32; off > 0; off >>= 1) t += __shfl_xor(t, off);
  if ((tid & 63) == 0) red[tid >> 6] = t;
  __syncthreads();
  if (tid == 0) psum[bh * NSEG + seg] = red[0] + red[1] + red[2] + red[3];

  const int d = tid & 63, grp = tid >> 6;
  const u16* vb = qkv + (size_t)b * L_SEQ * QKV_LD + h * D_HEAD + 2 * H_DIM + d;
  float acc = 0.f;
  #pragma unroll 4
  for (int i = 0; i < 64; i++) {
    const int ll = seg * 256 + grp * 64 + i;
    acc += es[grp * 64 + i] * bf2f(vb[(size_t)ll * QKV_LD]);
  }
  po[(((size_t)bh * NSEG + seg) * 4 + grp) * D_HEAD + d] = acc;
}

// Pass 3: combine NSEG*4 partials, normalize, write query row 0.
__global__ __launch_bounds__(64)
void attn_g_combine(const float* __restrict__ psum, const float* __restrict__ po,
                    u16* __restrict__ attnout)
{
  const int bh = blockIdx.x;
  const int b = bh / N_HEADS, h = bh % N_HEADS;
  const int d = threadIdx.x;
  float S = 0.f;
  #pragma unroll
  for (int i = 0; i < NSEG; i++) S += psum[bh * NSEG + i];
  float acc = 0.f;
  #pragma unroll
  for (int i = 0; i < NSEG * 4; i++)
    acc += po[((size_t)bh * NSEG * 4 + i) * D_HEAD + d];
  attnout[(size_t)b * L_SEQ * H_DIM + h * D_HEAD + d] = f2bf(acc / S);
}

// ---------------- LayerNorm kernels ----------------
__device__ __forceinline__ void block_stats(float sum, float sq, float* red,
                                            float& mean, float& rstd)
{
  const int lane = threadIdx.x & 63, wv = threadIdx.x >> 6;
  #pragma unroll
  for (int off = 32; off > 0; off >>= 1) {
    sum += __shfl_xor(sum, off);
    sq  += __shfl_xor(sq, off);
  }
  if (lane == 0) { red[wv] = sum; red[4 + wv] = sq; }
  __syncthreads();
  sum = red[0] + red[1] + red[2] + red[3];
  sq  = red[4] + red[5] + red[6] + red[7];
  mean = sum * (1.0f / H_DIM);
  const float var = sq * (1.0f / H_DIM) - mean * mean;
  rstd = rsqrtf(var + EPS_LN);
}

__global__ __launch_bounds__(256)
void embed_ln_kernel(const int* __restrict__ ids, const float* __restrict__ wemb,
                     const float* __restrict__ pemb, const float* __restrict__ gam,
                     const float* __restrict__ bet, float* __restrict__ xf,
                     u16* __restrict__ xb)
{
  __shared__ float red[8];
  const int row = blockIdx.x, tid = threadIdx.x;
  const int l = row & (L_SEQ - 1);
  const int id = ids[row];
  float v[3]; float sum = 0.f, sq = 0.f;
  #pragma unroll
  for (int i = 0; i < 3; i++) {
    const int c = tid + i * 256;
    const float t = wemb[(size_t)id * H_DIM + c] + pemb[(size_t)l * H_DIM + c];
    v[i] = t; sum += t; sq += t * t;
  }
  float mean, rstd;
  block_stats(sum, sq, red, mean, rstd);
  #pragma unroll
  for (int i = 0; i < 3; i++) {
    const int c = tid + i * 256;
    const float y = (v[i] - mean) * rstd * gam[c] + bet[c];
    xf[(size_t)row * H_DIM + c] = y;
    xb[(size_t)row * H_DIM + c] = f2bf(y);
  }
}

__global__ __launch_bounds__(256)
void add_ln_kernel(float* xio, const float* __restrict__ yin,
                   const float* __restrict__ gam, const float* __restrict__ bet,
                   u16* __restrict__ xb)
{
  __shared__ float red[8];
  const int row = blockIdx.x, tid = threadIdx.x;
  float v[3]; float sum = 0.f, sq = 0.f;
  #pragma unroll
  for (int i = 0; i < 3; i++) {
    const int c = tid + i * 256;
    const float t = xio[(size_t)row * H_DIM + c] + yin[(size_t)row * H_DIM + c];
    v[i] = t; sum += t; sq += t * t;
  }
  float mean, rstd;
  block_stats(sum, sq, red, mean, rstd);
  #pragma unroll
  for (int i = 0; i < 3; i++) {
    const int c = tid + i * 256;
    const float y = (v[i] - mean) * rstd * gam[c] + bet[c];
    xio[(size_t)row * H_DIM + c] = y;
    xb[(size_t)row * H_DIM + c] = f2bf(y);
  }
}

// ---------------- weight transpose fp32 -> bf16 (Wt[n][k] = W[k][n]) ----------------
__global__ __launch_bounds__(256)
void transpose_w_kernel(const float* __restrict__ W, u16* __restrict__ Wt, int K, int N)
{
  __shared__ float tile[32][33];
  const int k0 = blockIdx.x * 32, n0 = blockIdx.y * 32;
  const int tx = threadIdx.x & 31, ty = threadIdx.x >> 5;
  #pragma unroll
  for (int i = 0; i < 32; i += 8)
    tile[ty + i][tx] = W[(size_t)(k0 + ty + i) * N + n0 + tx];
  __syncthreads();
  #pragma unroll
  for (int i = 0; i < 32; i += 8)
    Wt[(size_t)(n0 + ty + i) * K + k0 + tx] = f2bf(tile[tx][ty + i]);
}

__global__ void concat3_kernel(const float* __restrict__ a, const float* __restrict__ b,
                               const float* __restrict__ c, float* __restrict__ out)
{
  const int i = blockIdx.x * 256 + threadIdx.x;
  if (i < H_DIM) out[i] = a[i];
  else if (i < 2 * H_DIM) out[i] = b[i - H_DIM];
  else if (i < 3 * H_DIM) out[i] = c[i - 2 * H_DIM];
}

__global__ void cls_copy_kernel(const float* __restrict__ vdn, float* __restrict__ cls)
{
  const int i = blockIdx.x * 256 + threadIdx.x;
  if (i < BATCH * OUT_DIM)
    cls[i] = vdn[(size_t)(i / OUT_DIM) * L_SEQ * OUT_DIM + (i % OUT_DIM)];
}

// ---------------- host ----------------
extern "C" void kernel_launch(void* const* d_in, const int* in_sizes, int n_in,
                              void* d_out, int out_size, void* d_ws, size_t ws_size,
                              hipStream_t stream)
{
  (void)in_sizes; (void)n_in; (void)out_size; (void)ws_size;
  const int*   ids   = (const int*)d_in[0];
  const int*   amask = (const int*)d_in[1];
  const float* wemb  = (const float*)d_in[2];
  const float* pemb  = (const float*)d_in[3];
  const float* elns  = (const float*)d_in[4];
  const float* elnb  = (const float*)d_in[5];
  const float* Wq    = (const float*)d_in[6];
  const float* bq    = (const float*)d_in[7];
  const float* Wk    = (const float*)d_in[8];
  const float* bk    = (const float*)d_in[9];
  const float* Wv    = (const float*)d_in[10];
  const float* bv    = (const float*)d_in[11];
  const float* Wo    = (const float*)d_in[12];
  const float* bo    = (const float*)d_in[13];
  const float* ln1s  = (const float*)d_in[14];
  const float* ln1b  = (const float*)d_in[15];
  const float* W1    = (const float*)d_in[16];
  const float* b1    = (const float*)d_in[17];
  const float* W2    = (const float*)d_in[18];
  const float* b2    = (const float*)d_in[19];
  const float* ln2s  = (const float*)d_in[20];
  const float* ln2b  = (const float*)d_in[21];
  const float* Wfc   = (const float*)d_in[22];
  const float* bfc   = (const float*)d_in[23];

  char* ws = (char*)d_ws;
  size_t off = 0;
  auto alloc = [&](size_t bytes) -> void* {
    void* p = ws + off;
    off += (bytes + 255) & ~(size_t)255;
    return p;
  };
  float* xf   = (float*)alloc((size_t)M_ROWS * H_DIM * 4);
  float* proj = (float*)alloc((size_t)M_ROWS * H_DIM * 4);
  u16* xb     = (u16*)alloc((size_t)M_ROWS * H_DIM * 2);
  u16* big    = (u16*)alloc((size_t)M_ROWS * FF_DIM * 2);  // qkv(2304) / ff1(3072) time-share
  u16* attno  = (u16*)alloc((size_t)M_ROWS * H_DIM * 2);
  u16* wqkvT  = (u16*)alloc((size_t)QKV_LD * H_DIM * 2);
  u16* woT    = (u16*)alloc((size_t)H_DIM * H_DIM * 2);
  u16* w1T    = (u16*)alloc((size_t)FF_DIM * H_DIM * 2);
  u16* w2T    = (u16*)alloc((size_t)H_DIM * FF_DIM * 2);
  u16* wfcT   = (u16*)alloc((size_t)OUT_DIM * H_DIM * 2);
  float* bqkv = (float*)alloc(QKV_LD * 4);
  float* gsc  = (float*)alloc((size_t)BATCH * N_HEADS * L_SEQ * 4);      // global-row scores
  float* gpm  = (float*)alloc((size_t)BATCH * N_HEADS * NSEG * 4);       // partial max
  float* gps  = (float*)alloc((size_t)BATCH * N_HEADS * NSEG * 4);       // partial expsum
  float* gpo  = (float*)alloc((size_t)BATCH * N_HEADS * NSEG * 4 * D_HEAD * 4); // partial o

  u16* qkvb = big;
  u16* ff1  = big;

  embed_ln_kernel<<<M_ROWS, 256, 0, stream>>>(ids, wemb, pemb, elns, elnb, xf, xb);

  for (int l = 0; l < 2; l++) {
    const size_t wof = (size_t)l * H_DIM * H_DIM;
    transpose_w_kernel<<<dim3(24, 24), 256, 0, stream>>>(Wq + wof, wqkvT, H_DIM, H_DIM);
    transpose_w_kernel<<<dim3(24, 24), 256, 0, stream>>>(Wk + wof, wqkvT + (size_t)H_DIM * H_DIM, H_DIM, H_DIM);
    transpose_w_kernel<<<dim3(24, 24), 256, 0, stream>>>(Wv + wof, wqkvT + (size_t)2 * H_DIM * H_DIM, H_DIM, H_DIM);
    transpose_w_kernel<<<dim3(24, 24), 256, 0, stream>>>(Wo + wof, woT, H_DIM, H_DIM);
    transpose_w_kernel<<<dim3(24, 96), 256, 0, stream>>>(W1 + (size_t)l * H_DIM * FF_DIM, w1T, H_DIM, FF_DIM);
    transpose_w_kernel<<<dim3(96, 24), 256, 0, stream>>>(W2 + (size_t)l * FF_DIM * H_DIM, w2T, FF_DIM, H_DIM);
    concat3_kernel<<<9, 256, 0, stream>>>(bq + l * H_DIM, bk + l * H_DIM, bv + l * H_DIM, bqkv);

    gemm_bf16_kernel<1, 0><<<(M_ROWS / 128) * (QKV_LD / 128), 256, 0, stream>>>(
        xb, wqkvT, bqkv, nullptr, qkvb, QKV_LD, H_DIM);
    attn_local_kernel<<<BATCH * N_HEADS * N_CHUNK, 512, 0, stream>>>(qkvb, amask, attno);
    attn_g_score<<<dim3(NSEG, BATCH * N_HEADS), 256, 0, stream>>>(qkvb, amask, gsc, gpm);
    attn_g_pv<<<dim3(NSEG, BATCH * N_HEADS), 256, 0, stream>>>(qkvb, gsc, gpm, gps, gpo);
    attn_g_combine<<<BATCH * N_HEADS, 64, 0, stream>>>(gps, gpo, attno);
    gemm_bf16_kernel<0, 0><<<(M_ROWS / 128) * (H_DIM / 128), 256, 0, stream>>>(
        attno, woT, bo + l * H_DIM, proj, nullptr, H_DIM, H_DIM);
    add_ln_kernel<<<M_ROWS, 256, 0, stream>>>(xf, proj, ln1s + l * H_DIM, ln1b + l * H_DIM, xb);
    gemm_bf16_kernel<1, 1><<<(M_ROWS / 128) * (FF_DIM / 128), 256, 0, stream>>>(
        xb, w1T, b1 + l * FF_DIM, nullptr, ff1, FF_DIM, H_DIM);
    gemm_bf16_kernel<0, 0><<<(M_ROWS / 128) * (H_DIM / 128), 256, 0, stream>>>(
        ff1, w2T, b2 + l * H_DIM, proj, nullptr, H_DIM, FF_DIM);
    add_ln_kernel<<<M_ROWS, 256, 0, stream>>>(xf, proj, ln2s + l * H_DIM, ln2b + l * H_DIM, xb);
  }

  transpose_w_kernel<<<dim3(24, 12), 256, 0, stream>>>(Wfc, wfcT, H_DIM, OUT_DIM);
  float* vdn = (float*)d_out;
  gemm_bf16_kernel<0, 0><<<(M_ROWS / 128) * (OUT_DIM / 128), 256, 0, stream>>>(
      xb, wfcT, bfc, vdn, nullptr, OUT_DIM, H_DIM);
  cls_copy_kernel<<<3, 256, 0, stream>>>(vdn, vdn + (size_t)BATCH * L_SEQ * OUT_DIM);
}